// Round 8
// baseline (95.835 us; speedup 1.0000x reference)
//
#include <hip/hip_runtime.h>

#define HSZ   16
#define TLEN  512
#define XPAD  4
#define LOG2E 1.4426950408889634f
#define K2    (-2.0f * LOG2E)

typedef _Float16 half2v __attribute__((ext_vector_type(2)));

// ws layout (floats): [0..1023] scaled W_hh [64][16]; [1024..1087] scaled W_ih; [1088..1151] scaled (b_ih+b_hh)
__global__ __launch_bounds__(64) void prep_kernel(
    const float* __restrict__ W_ih, const float* __restrict__ W_hh,
    const float* __restrict__ b_ih, const float* __restrict__ b_hh,
    float* __restrict__ ws)
{
    const int r = threadIdx.x;  // 0..63 gate row, torch order i,f,g,o
    const float s = (r >= 32 && r < 48) ? (-2.0f * LOG2E) : (-LOG2E);  // tanh rows get -2*log2e
    #pragma unroll
    for (int k = 0; k < HSZ; ++k) ws[r * HSZ + k] = s * W_hh[r * HSZ + k];
    ws[1024 + r] = s * W_ih[r];
    ws[1088 + r] = s * (b_ih[r] + b_hh[r]);
}

// DPP row-rotate within 16-lane rows (VALU pipe — no LDS). Lane maps are discovered at
// runtime via lane-ID probes, so the rotate convention can't silently break correctness.
template<int N>
__device__ __forceinline__ int dpp_ror_i(int v) {
    return __builtin_amdgcn_update_dpp(v, v, 0x120 | N, 0xF, 0xF, false);
}
template<int N>
__device__ __forceinline__ float dpp_ror_f(float v) {
    return __int_as_float(dpp_ror_i<N>(__float_as_int(v)));
}

// 16 lanes per batch element; lane j owns gate rows {j,16+j,32+j,48+j}=(i,f,g,o)_j plus
// cs_j,h_j (all lane-local; cs = -2log2e * c). h broadcast: pack (h,h_ror1) to half2,
// 7 packed DPP rotations; matvec = 8 v_dot2_f32_f16 per gate (2 chains of 4).
// Cell update uses ONE rcp: c' = [c*(1+eI)(1+eG) + (1-eG)(1+eF)]/[(1+eF)(1+eI)(1+eG)],
// kept pre-scaled by -2log2e so exp2(cs) = e^{-2c} feeds tanh directly. 4 batches/wave.
__global__ __launch_bounds__(64) void lstm_kernel(
    const float* __restrict__ x, const float* __restrict__ ws,
    const float* __restrict__ W_lin, float* __restrict__ out)
{
    __shared__ __align__(16) float xs[4 * (TLEN + XPAD)];

    const int tid = threadIdx.x;
    const int g   = tid >> 4;   // batch slot within wave (0..3)
    const int j   = tid & 15;   // hidden index / lane within 16-lane group

    // stage x for 4 batches (coalesced float4 from global; padded rows in LDS)
    {
        const float4* xv = (const float4*)(x + (long)blockIdx.x * (4 * TLEN));
        #pragma unroll
        for (int b = 0; b < 4; ++b) {
            float4* dst = (float4*)(xs + b * (TLEN + XPAD));
            #pragma unroll
            for (int i = 0; i < 2; ++i)
                dst[i * 64 + tid] = xv[b * 128 + i * 64 + tid];
        }
    }
    __syncthreads();

    // Discover DPP source-lane maps. P0 at lane j = (h[j], h[s1[j]]) where s1 = ror1 src.
    // Pm = ror<2m>(P0): lane j gets (h[lo_m[j]], h[hi_m[j]]).
    const int s1 = dpp_ror_i<1>(j);
    int lo[8], hi[8];
    lo[0] = j;                  hi[0] = s1;
    lo[1] = dpp_ror_i<2>(j);    hi[1] = dpp_ror_i<2>(s1);
    lo[2] = dpp_ror_i<4>(j);    hi[2] = dpp_ror_i<4>(s1);
    lo[3] = dpp_ror_i<6>(j);    hi[3] = dpp_ror_i<6>(s1);
    lo[4] = dpp_ror_i<8>(j);    hi[4] = dpp_ror_i<8>(s1);
    lo[5] = dpp_ror_i<10>(j);   hi[5] = dpp_ror_i<10>(s1);
    lo[6] = dpp_ror_i<12>(j);   hi[6] = dpp_ror_i<12>(s1);
    lo[7] = dpp_ror_i<14>(j);   hi[7] = dpp_ror_i<14>(s1);

    // permutation-matched f16 weight pairs (RNE rounding via cast); scales baked in ws
    half2v wI[8], wF[8], wG[8], wO[8];
    #pragma unroll
    for (int m = 0; m < 8; ++m) {
        wI[m].x = (_Float16)ws[(     j) * HSZ + lo[m]];  wI[m].y = (_Float16)ws[(     j) * HSZ + hi[m]];
        wF[m].x = (_Float16)ws[(16 + j) * HSZ + lo[m]];  wF[m].y = (_Float16)ws[(16 + j) * HSZ + hi[m]];
        wG[m].x = (_Float16)ws[(32 + j) * HSZ + lo[m]];  wG[m].y = (_Float16)ws[(32 + j) * HSZ + hi[m]];
        wO[m].x = (_Float16)ws[(48 + j) * HSZ + lo[m]];  wO[m].y = (_Float16)ws[(48 + j) * HSZ + hi[m]];
    }
    const float wi0 = ws[1024 + j],      wi1 = ws[1024 + 16 + j];
    const float wi2 = ws[1024 + 32 + j], wi3 = ws[1024 + 48 + j];
    const float bb0 = ws[1088 + j],      bb1 = ws[1088 + 16 + j];
    const float bb2 = ws[1088 + 32 + j], bb3 = ws[1088 + 48 + j];

    const float* xrow = xs + g * (TLEN + XPAD);
    float cs = 0.0f, h = 0.0f;   // cs = -2log2e * c

    #define STEP(XT) {                                                            \
        const float hr1 = dpp_ror_f<1>(h);                                        \
        half2v P0h; P0h.x = (_Float16)h; P0h.y = (_Float16)hr1;                   \
        const int q0 = __builtin_bit_cast(int, P0h);                              \
        const int q1 = dpp_ror_i<2>(q0),  q2 = dpp_ror_i<4>(q0);                  \
        const int q3 = dpp_ror_i<6>(q0),  q4 = dpp_ror_i<8>(q0);                  \
        const int q5 = dpp_ror_i<10>(q0), q6 = dpp_ror_i<12>(q0);                 \
        const int q7 = dpp_ror_i<14>(q0);                                         \
        const half2v P[8] = {                                                     \
            P0h,                            __builtin_bit_cast(half2v, q1),       \
            __builtin_bit_cast(half2v, q2), __builtin_bit_cast(half2v, q3),       \
            __builtin_bit_cast(half2v, q4), __builtin_bit_cast(half2v, q5),       \
            __builtin_bit_cast(half2v, q6), __builtin_bit_cast(half2v, q7) };     \
        float aI0 = fmaf(XT, wi0, bb0), aI1 = 0.0f;                               \
        float aF0 = fmaf(XT, wi1, bb1), aF1 = 0.0f;                               \
        float aG0 = fmaf(XT, wi2, bb2), aG1 = 0.0f;                               \
        float aO0 = fmaf(XT, wi3, bb3), aO1 = 0.0f;                               \
        _Pragma("unroll")                                                         \
        for (int m = 0; m < 4; ++m) {                                             \
            aI0 = __builtin_amdgcn_fdot2(P[m], wI[m], aI0, false);                \
            aI1 = __builtin_amdgcn_fdot2(P[m+4], wI[m+4], aI1, false);            \
            aF0 = __builtin_amdgcn_fdot2(P[m], wF[m], aF0, false);                \
            aF1 = __builtin_amdgcn_fdot2(P[m+4], wF[m+4], aF1, false);            \
            aG0 = __builtin_amdgcn_fdot2(P[m], wG[m], aG0, false);                \
            aG1 = __builtin_amdgcn_fdot2(P[m+4], wG[m+4], aG1, false);            \
            aO0 = __builtin_amdgcn_fdot2(P[m], wO[m], aO0, false);                \
            aO1 = __builtin_amdgcn_fdot2(P[m+4], wO[m+4], aO1, false);            \
        }                                                                         \
        const float eG = __builtin_amdgcn_exp2f(aG0 + aG1);  /* e^{-2zg} */       \
        const float eI = __builtin_amdgcn_exp2f(aI0 + aI1);  /* e^{-zi}  */       \
        const float eF = __builtin_amdgcn_exp2f(aF0 + aF1);                       \
        const float eO = __builtin_amdgcn_exp2f(aO0 + aO1);                       \
        const float pI = 1.0f + eI, pF = 1.0f + eF, pG = 1.0f + eG, pO = 1.0f + eO; \
        const float u   = pI * pG;                                                \
        const float r   = __builtin_amdgcn_rcpf(pF * u);                          \
        const float tG  = fmaf(K2, eG, -K2);     /* K2*(1-eG) = -K2 + K2*eG... */ \
        const float num = fmaf(cs, u, (-tG) * pF); /* cs*u + K2*(1-eG)*pF */      \
        cs = num * r;                                                             \
        const float eC = __builtin_amdgcn_exp2f(cs);         /* e^{-2c} */        \
        const float rh = __builtin_amdgcn_rcpf(pO * (1.0f + eC));                 \
        h = (1.0f - eC) * rh;                    /* o * tanh(c) */                \
    }

    #pragma unroll 1
    for (int t4 = 0; t4 < TLEN / 4; ++t4) {
        const float4 xq = *(const float4*)(xrow + 4 * t4);  // one LDS read per 4 steps
        STEP(xq.x)
        STEP(xq.y)
        STEP(xq.z)
        STEP(xq.w)
    }
    #undef STEP

    // out[b] = sum_j h_j * W_lin[j] (16-lane reduce within the group)
    float v = h * W_lin[j];
    v += __shfl_xor(v, 1);
    v += __shfl_xor(v, 2);
    v += __shfl_xor(v, 4);
    v += __shfl_xor(v, 8);
    if (j == 0) out[blockIdx.x * 4 + g] = v;
}

extern "C" void kernel_launch(void* const* d_in, const int* in_sizes, int n_in,
                              void* d_out, int out_size, void* d_ws, size_t ws_size,
                              hipStream_t stream) {
    const float* x     = (const float*)d_in[0];
    const float* W_ih  = (const float*)d_in[1];
    const float* W_hh  = (const float*)d_in[2];
    const float* b_ih  = (const float*)d_in[3];
    const float* b_hh  = (const float*)d_in[4];
    const float* W_lin = (const float*)d_in[5];
    float* out = (float*)d_out;
    float* ws  = (float*)d_ws;

    const int B = in_sizes[0] / TLEN;  // 4096

    hipLaunchKernelGGL(prep_kernel, dim3(1), dim3(64), 0, stream,
                       W_ih, W_hh, b_ih, b_hh, ws);
    hipLaunchKernelGGL(lstm_kernel, dim3(B / 4), dim3(64), 0, stream,
                       x, ws, W_lin, out);
}

// Round 9
// 95.422 us; speedup vs baseline: 1.0043x; 1.0043x over previous
//
#include <hip/hip_runtime.h>

#define HSZ   16
#define TLEN  512
#define XPAD  4
#define LOG2E 1.4426950408889634f
#define K2    (-2.0f * LOG2E)

typedef _Float16 half2v __attribute__((ext_vector_type(2)));

// ws layout (floats): [0..1023] scaled W_hh [64][16]; [1024..1087] scaled W_ih; [1088..1151] scaled (b_ih+b_hh)
__global__ __launch_bounds__(64) void prep_kernel(
    const float* __restrict__ W_ih, const float* __restrict__ W_hh,
    const float* __restrict__ b_ih, const float* __restrict__ b_hh,
    float* __restrict__ ws)
{
    const int r = threadIdx.x;  // 0..63 gate row, torch order i,f,g,o
    const float s = (r >= 32 && r < 48) ? (-2.0f * LOG2E) : (-LOG2E);  // tanh rows get -2*log2e
    #pragma unroll
    for (int k = 0; k < HSZ; ++k) ws[r * HSZ + k] = s * W_hh[r * HSZ + k];
    ws[1024 + r] = s * W_ih[r];
    ws[1088 + r] = s * (b_ih[r] + b_hh[r]);
}

// DPP row-rotate within 16-lane rows (VALU pipe — no LDS). Lane maps are discovered at
// runtime via lane-ID probes, so the rotate convention can't silently break correctness.
template<int N>
__device__ __forceinline__ int dpp_ror_i(int v) {
    return __builtin_amdgcn_update_dpp(v, v, 0x120 | N, 0xF, 0xF, false);
}
template<int N>
__device__ __forceinline__ float dpp_ror_f(float v) {
    return __int_as_float(dpp_ror_i<N>(__float_as_int(v)));
}

// 16 lanes per batch element; lane j owns gate rows {j,16+j,32+j,48+j}=(i,f,g,o)_j plus
// cs_j,h_j (lane-local; cs = -2log2e * c so exp2(cs)=e^{-2c}). h broadcast: pack
// (h,h_ror1) to half2, 7 packed DPP rotations; matvec = 8 v_dot2_f32_f16 per gate
// (2 chains of 4). Cell update keeps R7's short chain: gf=rcp(1+eF); cs=fmaf(gf,cs,pK).
// x is software-pipelined (prefetch next float4; XPAD makes the overrun read safe).
__global__ __launch_bounds__(64) void lstm_kernel(
    const float* __restrict__ x, const float* __restrict__ ws,
    const float* __restrict__ W_lin, float* __restrict__ out)
{
    __shared__ __align__(16) float xs[4 * (TLEN + XPAD)];

    const int tid = threadIdx.x;
    const int g   = tid >> 4;   // batch slot within wave (0..3)
    const int j   = tid & 15;   // hidden index / lane within 16-lane group

    // stage x for 4 batches (coalesced float4 from global; padded rows in LDS)
    {
        const float4* xv = (const float4*)(x + (long)blockIdx.x * (4 * TLEN));
        #pragma unroll
        for (int b = 0; b < 4; ++b) {
            float4* dst = (float4*)(xs + b * (TLEN + XPAD));
            #pragma unroll
            for (int i = 0; i < 2; ++i)
                dst[i * 64 + tid] = xv[b * 128 + i * 64 + tid];
        }
    }
    __syncthreads();

    // Discover DPP source-lane maps. P0 at lane j = (h[j], h[s1[j]]) where s1 = ror1 src.
    // Pm = ror<2m>(P0): lane j gets (h[lo_m[j]], h[hi_m[j]]).
    const int s1 = dpp_ror_i<1>(j);
    int lo[8], hi[8];
    lo[0] = j;                  hi[0] = s1;
    lo[1] = dpp_ror_i<2>(j);    hi[1] = dpp_ror_i<2>(s1);
    lo[2] = dpp_ror_i<4>(j);    hi[2] = dpp_ror_i<4>(s1);
    lo[3] = dpp_ror_i<6>(j);    hi[3] = dpp_ror_i<6>(s1);
    lo[4] = dpp_ror_i<8>(j);    hi[4] = dpp_ror_i<8>(s1);
    lo[5] = dpp_ror_i<10>(j);   hi[5] = dpp_ror_i<10>(s1);
    lo[6] = dpp_ror_i<12>(j);   hi[6] = dpp_ror_i<12>(s1);
    lo[7] = dpp_ror_i<14>(j);   hi[7] = dpp_ror_i<14>(s1);

    // permutation-matched f16 weight pairs (RNE rounding via cast); scales baked in ws
    half2v wI[8], wF[8], wG[8], wO[8];
    #pragma unroll
    for (int m = 0; m < 8; ++m) {
        wI[m].x = (_Float16)ws[(     j) * HSZ + lo[m]];  wI[m].y = (_Float16)ws[(     j) * HSZ + hi[m]];
        wF[m].x = (_Float16)ws[(16 + j) * HSZ + lo[m]];  wF[m].y = (_Float16)ws[(16 + j) * HSZ + hi[m]];
        wG[m].x = (_Float16)ws[(32 + j) * HSZ + lo[m]];  wG[m].y = (_Float16)ws[(32 + j) * HSZ + hi[m]];
        wO[m].x = (_Float16)ws[(48 + j) * HSZ + lo[m]];  wO[m].y = (_Float16)ws[(48 + j) * HSZ + hi[m]];
    }
    const float wi0 = ws[1024 + j],      wi1 = ws[1024 + 16 + j];
    const float wi2 = ws[1024 + 32 + j], wi3 = ws[1024 + 48 + j];
    const float bb0 = ws[1088 + j],      bb1 = ws[1088 + 16 + j];
    const float bb2 = ws[1088 + 32 + j], bb3 = ws[1088 + 48 + j];

    const float* xrow = xs + g * (TLEN + XPAD);
    float cs = 0.0f, h = 0.0f;   // cs = -2log2e * c

    #define STEP(XT) {                                                            \
        const float hr1 = dpp_ror_f<1>(h);                                        \
        half2v P0h; P0h.x = (_Float16)h; P0h.y = (_Float16)hr1;                   \
        const int q0 = __builtin_bit_cast(int, P0h);                              \
        const int q1 = dpp_ror_i<2>(q0),  q2 = dpp_ror_i<4>(q0);                  \
        const int q3 = dpp_ror_i<6>(q0),  q4 = dpp_ror_i<8>(q0);                  \
        const int q5 = dpp_ror_i<10>(q0), q6 = dpp_ror_i<12>(q0);                 \
        const int q7 = dpp_ror_i<14>(q0);                                         \
        const half2v P[8] = {                                                     \
            P0h,                            __builtin_bit_cast(half2v, q1),       \
            __builtin_bit_cast(half2v, q2), __builtin_bit_cast(half2v, q3),       \
            __builtin_bit_cast(half2v, q4), __builtin_bit_cast(half2v, q5),       \
            __builtin_bit_cast(half2v, q6), __builtin_bit_cast(half2v, q7) };     \
        float aI0 = fmaf(XT, wi0, bb0), aI1 = 0.0f;                               \
        float aF0 = fmaf(XT, wi1, bb1), aF1 = 0.0f;                               \
        float aG0 = fmaf(XT, wi2, bb2), aG1 = 0.0f;                               \
        float aO0 = fmaf(XT, wi3, bb3), aO1 = 0.0f;                               \
        _Pragma("unroll")                                                         \
        for (int m = 0; m < 4; ++m) {                                             \
            aI0 = __builtin_amdgcn_fdot2(P[m], wI[m], aI0, false);                \
            aI1 = __builtin_amdgcn_fdot2(P[m+4], wI[m+4], aI1, false);            \
            aG0 = __builtin_amdgcn_fdot2(P[m], wG[m], aG0, false);                \
            aG1 = __builtin_amdgcn_fdot2(P[m+4], wG[m+4], aG1, false);            \
            aF0 = __builtin_amdgcn_fdot2(P[m], wF[m], aF0, false);                \
            aF1 = __builtin_amdgcn_fdot2(P[m+4], wF[m+4], aF1, false);            \
            aO0 = __builtin_amdgcn_fdot2(P[m], wO[m], aO0, false);                \
            aO1 = __builtin_amdgcn_fdot2(P[m+4], wO[m+4], aO1, false);            \
        }                                                                         \
        const float eI = __builtin_amdgcn_exp2f(aI0 + aI1);  /* e^{-zi}  */       \
        const float eG = __builtin_amdgcn_exp2f(aG0 + aG1);  /* e^{-2zg} */       \
        const float eF = __builtin_amdgcn_exp2f(aF0 + aF1);                       \
        const float eO = __builtin_amdgcn_exp2f(aO0 + aO1);                       \
        const float pI = 1.0f + eI, pG = 1.0f + eG;                               \
        const float tGn = fmaf(-(K2), eG, (K2));   /* K2*(1-eG), K2<0 */          \
        const float rp  = __builtin_amdgcn_rcpf(pI * pG);                         \
        const float pK  = tGn * rp;                /* K2 * i * tanh(g) */         \
        const float gf  = __builtin_amdgcn_rcpf(1.0f + eF);                       \
        cs = fmaf(gf, cs, pK);                     /* K2*(f*c + i*g~) */          \
        const float eC = __builtin_amdgcn_exp2f(cs);          /* e^{-2c} */       \
        const float rh = __builtin_amdgcn_rcpf((1.0f + eO) * (1.0f + eC));        \
        h = (1.0f - eC) * rh;                      /* o * tanh(c) */              \
    }

    float4 xq = *(const float4*)(xrow);
    #pragma unroll 1
    for (int t4 = 0; t4 < TLEN / 4; ++t4) {
        const float4 xc = xq;
        xq = *(const float4*)(xrow + 4 * t4 + 4);  // prefetch next quad (pad-safe overrun)
        STEP(xc.x)
        STEP(xc.y)
        STEP(xc.z)
        STEP(xc.w)
    }
    #undef STEP

    // out[b] = sum_j h_j * W_lin[j] (16-lane reduce within the group)
    float v = h * W_lin[j];
    v += __shfl_xor(v, 1);
    v += __shfl_xor(v, 2);
    v += __shfl_xor(v, 4);
    v += __shfl_xor(v, 8);
    if (j == 0) out[blockIdx.x * 4 + g] = v;
}

extern "C" void kernel_launch(void* const* d_in, const int* in_sizes, int n_in,
                              void* d_out, int out_size, void* d_ws, size_t ws_size,
                              hipStream_t stream) {
    const float* x     = (const float*)d_in[0];
    const float* W_ih  = (const float*)d_in[1];
    const float* W_hh  = (const float*)d_in[2];
    const float* b_ih  = (const float*)d_in[3];
    const float* b_hh  = (const float*)d_in[4];
    const float* W_lin = (const float*)d_in[5];
    float* out = (float*)d_out;
    float* ws  = (float*)d_ws;

    const int B = in_sizes[0] / TLEN;  // 4096

    hipLaunchKernelGGL(prep_kernel, dim3(1), dim3(64), 0, stream,
                       W_ih, W_hh, b_ih, b_hh, ws);
    hipLaunchKernelGGL(lstm_kernel, dim3(B / 4), dim3(64), 0, stream,
                       x, ws, W_lin, out);
}

// Round 10
// 91.712 us; speedup vs baseline: 1.0450x; 1.0405x over previous
//
#include <hip/hip_runtime.h>

#define HSZ   16
#define TLEN  512
#define XPAD  4
#define LOG2E 1.4426950408889634f
#define K2    (-2.0f * LOG2E)

typedef _Float16 half2v __attribute__((ext_vector_type(2)));

// ws layout (floats): [0..1023] scaled W_hh [64][16]; [1024..1087] scaled W_ih; [1088..1151] scaled (b_ih+b_hh)
__global__ __launch_bounds__(64) void prep_kernel(
    const float* __restrict__ W_ih, const float* __restrict__ W_hh,
    const float* __restrict__ b_ih, const float* __restrict__ b_hh,
    float* __restrict__ ws)
{
    const int r = threadIdx.x;  // 0..63 gate row, torch order i,f,g,o
    const float s = (r >= 32 && r < 48) ? (-2.0f * LOG2E) : (-LOG2E);  // tanh rows get -2*log2e
    #pragma unroll
    for (int k = 0; k < HSZ; ++k) ws[r * HSZ + k] = s * W_hh[r * HSZ + k];
    ws[1024 + r] = s * W_ih[r];
    ws[1088 + r] = s * (b_ih[r] + b_hh[r]);
}

// DPP row-rotate within 16-lane rows (VALU pipe — no LDS). Lane maps are discovered at
// runtime via lane-ID probes, so the rotate convention can't silently break correctness.
template<int N>
__device__ __forceinline__ int dpp_ror_i(int v) {
    return __builtin_amdgcn_update_dpp(v, v, 0x120 | N, 0xF, 0xF, false);
}
template<int N>
__device__ __forceinline__ float dpp_ror_f(float v) {
    return __int_as_float(dpp_ror_i<N>(__float_as_int(v)));
}

// 16 lanes per batch element; lane j owns gate rows {j,16+j,32+j,48+j}=(i,f,g,o)_j plus
// c_j,h_j (all lane-local). h broadcast: pack (h, h_ror1) to half2 once, then 7 packed
// DPP rotations; matvec = 8 v_dot2_f32_f16 per gate with permutation-matched f16 weight
// pairs. Activations fused: gi*gg and go*tanh(c) each share one rcp. 4 batches/wave.
__global__ __launch_bounds__(64) void lstm_kernel(
    const float* __restrict__ x, const float* __restrict__ ws,
    const float* __restrict__ W_lin, float* __restrict__ out)
{
    __shared__ __align__(16) float xs[4 * (TLEN + XPAD)];

    const int tid = threadIdx.x;
    const int g   = tid >> 4;   // batch slot within wave (0..3)
    const int j   = tid & 15;   // hidden index / lane within 16-lane group

    // stage x for 4 batches (coalesced float4 from global; padded rows in LDS)
    {
        const float4* xv = (const float4*)(x + (long)blockIdx.x * (4 * TLEN));
        #pragma unroll
        for (int b = 0; b < 4; ++b) {
            float4* dst = (float4*)(xs + b * (TLEN + XPAD));
            #pragma unroll
            for (int i = 0; i < 2; ++i)
                dst[i * 64 + tid] = xv[b * 128 + i * 64 + tid];
        }
    }
    __syncthreads();

    // Discover DPP source-lane maps. P0 at lane j = (h[j], h[s1[j]]) where s1 = ror1 src.
    // Pm = ror<2m>(P0): lane j gets (h[lo_m[j]], h[hi_m[j]]), lo_m[j]=ror2m src,
    // hi_m[j]=s1 value AT that lane = dpp_ror<2m>(s1).
    const int s1 = dpp_ror_i<1>(j);
    int lo[8], hi[8];
    lo[0] = j;                  hi[0] = s1;
    lo[1] = dpp_ror_i<2>(j);    hi[1] = dpp_ror_i<2>(s1);
    lo[2] = dpp_ror_i<4>(j);    hi[2] = dpp_ror_i<4>(s1);
    lo[3] = dpp_ror_i<6>(j);    hi[3] = dpp_ror_i<6>(s1);
    lo[4] = dpp_ror_i<8>(j);    hi[4] = dpp_ror_i<8>(s1);
    lo[5] = dpp_ror_i<10>(j);   hi[5] = dpp_ror_i<10>(s1);
    lo[6] = dpp_ror_i<12>(j);   hi[6] = dpp_ror_i<12>(s1);
    lo[7] = dpp_ror_i<14>(j);   hi[7] = dpp_ror_i<14>(s1);

    // permutation-matched f16 weight pairs (RNE rounding via cast); scales baked in ws
    half2v wI[8], wF[8], wG[8], wO[8];
    #pragma unroll
    for (int m = 0; m < 8; ++m) {
        wI[m].x = (_Float16)ws[(     j) * HSZ + lo[m]];  wI[m].y = (_Float16)ws[(     j) * HSZ + hi[m]];
        wF[m].x = (_Float16)ws[(16 + j) * HSZ + lo[m]];  wF[m].y = (_Float16)ws[(16 + j) * HSZ + hi[m]];
        wG[m].x = (_Float16)ws[(32 + j) * HSZ + lo[m]];  wG[m].y = (_Float16)ws[(32 + j) * HSZ + hi[m]];
        wO[m].x = (_Float16)ws[(48 + j) * HSZ + lo[m]];  wO[m].y = (_Float16)ws[(48 + j) * HSZ + hi[m]];
    }
    const float wi0 = ws[1024 + j],      wi1 = ws[1024 + 16 + j];
    const float wi2 = ws[1024 + 32 + j], wi3 = ws[1024 + 48 + j];
    const float bb0 = ws[1088 + j],      bb1 = ws[1088 + 16 + j];
    const float bb2 = ws[1088 + 32 + j], bb3 = ws[1088 + 48 + j];

    const float* xrow = xs + g * (TLEN + XPAD);
    float c = 0.0f, h = 0.0f;

    #define STEP(XT) {                                                            \
        const float hr1 = dpp_ror_f<1>(h);                                        \
        half2v P0h; P0h.x = (_Float16)h; P0h.y = (_Float16)hr1;                   \
        const int q0 = __builtin_bit_cast(int, P0h);                              \
        const int q1 = dpp_ror_i<2>(q0),  q2 = dpp_ror_i<4>(q0);                  \
        const int q3 = dpp_ror_i<6>(q0),  q4 = dpp_ror_i<8>(q0);                  \
        const int q5 = dpp_ror_i<10>(q0), q6 = dpp_ror_i<12>(q0);                 \
        const int q7 = dpp_ror_i<14>(q0);                                         \
        const half2v P[8] = {                                                     \
            P0h,                          __builtin_bit_cast(half2v, q1),         \
            __builtin_bit_cast(half2v, q2), __builtin_bit_cast(half2v, q3),       \
            __builtin_bit_cast(half2v, q4), __builtin_bit_cast(half2v, q5),       \
            __builtin_bit_cast(half2v, q6), __builtin_bit_cast(half2v, q7) };     \
        float aI = fmaf(XT, wi0, bb0);                                            \
        float aF = fmaf(XT, wi1, bb1);                                            \
        float aG = fmaf(XT, wi2, bb2);                                            \
        float aO = fmaf(XT, wi3, bb3);                                            \
        _Pragma("unroll")                                                         \
        for (int m = 0; m < 8; ++m) {                                             \
            aI = __builtin_amdgcn_fdot2(P[m], wI[m], aI, false);                  \
            aF = __builtin_amdgcn_fdot2(P[m], wF[m], aF, false);                  \
            aG = __builtin_amdgcn_fdot2(P[m], wG[m], aG, false);                  \
            aO = __builtin_amdgcn_fdot2(P[m], wO[m], aO, false);                  \
        }                                                                         \
        const float eI = __builtin_amdgcn_exp2f(aI);   /* e^{-zi} */              \
        const float eF = __builtin_amdgcn_exp2f(aF);                              \
        const float eG = __builtin_amdgcn_exp2f(aG);   /* e^{-2zg} */             \
        const float eO = __builtin_amdgcn_exp2f(aO);                              \
        const float gf = __builtin_amdgcn_rcpf(1.0f + eF);                        \
        const float p  = (1.0f - eG) * __builtin_amdgcn_rcpf((1.0f + eI) * (1.0f + eG)); \
        c = fmaf(gf, c, p);                            /* f*c + i*tanh(g) */      \
        const float eC = __builtin_amdgcn_exp2f(c * (-2.0f * LOG2E));             \
        h = (1.0f - eC) * __builtin_amdgcn_rcpf((1.0f + eO) * (1.0f + eC));       \
    }

    #pragma unroll 1
    for (int t4 = 0; t4 < TLEN / 4; ++t4) {
        const float4 xq = *(const float4*)(xrow + 4 * t4);  // one LDS read per 4 steps
        STEP(xq.x)
        STEP(xq.y)
        STEP(xq.z)
        STEP(xq.w)
    }
    #undef STEP

    // out[b] = sum_j h_j * W_lin[j] (16-lane reduce within the group)
    float v = h * W_lin[j];
    v += __shfl_xor(v, 1);
    v += __shfl_xor(v, 2);
    v += __shfl_xor(v, 4);
    v += __shfl_xor(v, 8);
    if (j == 0) out[blockIdx.x * 4 + g] = v;
}

extern "C" void kernel_launch(void* const* d_in, const int* in_sizes, int n_in,
                              void* d_out, int out_size, void* d_ws, size_t ws_size,
                              hipStream_t stream) {
    const float* x     = (const float*)d_in[0];
    const float* W_ih  = (const float*)d_in[1];
    const float* W_hh  = (const float*)d_in[2];
    const float* b_ih  = (const float*)d_in[3];
    const float* b_hh  = (const float*)d_in[4];
    const float* W_lin = (const float*)d_in[5];
    float* out = (float*)d_out;
    float* ws  = (float*)d_ws;

    const int B = in_sizes[0] / TLEN;  // 4096

    hipLaunchKernelGGL(prep_kernel, dim3(1), dim3(64), 0, stream,
                       W_ih, W_hh, b_ih, b_hh, ws);
    hipLaunchKernelGGL(lstm_kernel, dim3(B / 4), dim3(64), 0, stream,
                       x, ws, W_lin, out);
}